// Round 3
// baseline (527.021 us; speedup 1.0000x reference)
//
#include <hip/hip_runtime.h>

#define HW (512 * 512)
#define NBINS 256
#define NB 128                       // batch
#define P1_BLOCKS_X 8                // blocks per batch image
#define PX_PER_THREAD 128            // 8 chunks of 16 px

// ---------------- counts histogram (batch-independent) ----------------
__global__ __launch_bounds__(256) void counts_kernel(const int* __restrict__ bins,
                                                     int* __restrict__ counts) {
    __shared__ int h[NBINS];
    const int tid = threadIdx.x;
    h[tid] = 0;
    __syncthreads();
    // 256 blocks * 256 threads * 1 int4 = HW ints
    int4 v = ((const int4*)bins)[blockIdx.x * 256 + tid];
    if (v.x > 3 && v.x < NBINS) atomicAdd(&h[v.x], 1);
    if (v.y > 3 && v.y < NBINS) atomicAdd(&h[v.y], 1);
    if (v.z > 3 && v.z < NBINS) atomicAdd(&h[v.z], 1);
    if (v.w > 3 && v.w < NBINS) atomicAdd(&h[v.w], 1);
    __syncthreads();
    if (h[tid]) atomicAdd(&counts[tid], h[tid]);
}

// ---------------- pass 1: per-(batch,bin) S1 = sum|n|, S2 = sum n^2 ----------------
// 32 privatized histogram copies; copy c = lane&31. Bin stored at rotated index
// (bin+c)&255 so bank = (bin+c)%32: when all lanes share one bin (ring tangent)
// banks are perfectly spread (2-way, free). Same-address collisions limited to
// lane pairs (i, i+32) -> handled by HW ds_add_f32 via unsafeAtomicAdd.
__device__ __forceinline__ void px_acc(float p, float q, int bv, int c,
                                       float* __restrict__ h1, float* __restrict__ h2) {
    float n = p - q;
    if (bv > 3 && bv < NBINS) {
        int j = (bv + c) & 255;
        unsafeAtomicAdd(&h1[j], fabsf(n));
        unsafeAtomicAdd(&h2[j], n * n);
    }
}

__global__ __launch_bounds__(256) void pass1(const float* __restrict__ parts,
                                             const float* __restrict__ projs,
                                             const int* __restrict__ bins,
                                             float* __restrict__ S1,
                                             float* __restrict__ S2) {
    __shared__ float h[2][32][NBINS];    // 64 KB: [s1|s2][copy][rotated bin]
    const int tid = threadIdx.x;
    const int c = tid & 31;

    // zero 16384 floats = 4096 float4
    float4* hz = (float4*)&h[0][0][0];
    #pragma unroll
    for (int k = 0; k < 16; ++k) hz[k * 256 + tid] = make_float4(0.f, 0.f, 0.f, 0.f);
    __syncthreads();

    const int b = blockIdx.y;
    const float4* __restrict__ p4 = (const float4*)parts + (size_t)b * (HW / 4);
    const float4* __restrict__ q4 = (const float4*)projs + (size_t)b * (HW / 4);
    const int4*  __restrict__ b4 = (const int4*)bins;
    const int blockBase = blockIdx.x * (256 * PX_PER_THREAD);   // pixels

    float* __restrict__ h1 = &h[0][c][0];
    float* __restrict__ h2 = &h[1][c][0];

    for (int m = 0; m < PX_PER_THREAD / 16; ++m) {
        const int f4 = (blockBase + m * (256 * 16) + tid * 16) >> 2;  // float4 index
        float4 P0 = p4[f4 + 0], P1 = p4[f4 + 1], P2 = p4[f4 + 2], P3 = p4[f4 + 3];
        float4 Q0 = q4[f4 + 0], Q1 = q4[f4 + 1], Q2 = q4[f4 + 2], Q3 = q4[f4 + 3];
        int4  B0 = b4[f4 + 0], B1 = b4[f4 + 1], B2 = b4[f4 + 2], B3 = b4[f4 + 3];

        px_acc(P0.x, Q0.x, B0.x, c, h1, h2); px_acc(P0.y, Q0.y, B0.y, c, h1, h2);
        px_acc(P0.z, Q0.z, B0.z, c, h1, h2); px_acc(P0.w, Q0.w, B0.w, c, h1, h2);
        px_acc(P1.x, Q1.x, B1.x, c, h1, h2); px_acc(P1.y, Q1.y, B1.y, c, h1, h2);
        px_acc(P1.z, Q1.z, B1.z, c, h1, h2); px_acc(P1.w, Q1.w, B1.w, c, h1, h2);
        px_acc(P2.x, Q2.x, B2.x, c, h1, h2); px_acc(P2.y, Q2.y, B2.y, c, h1, h2);
        px_acc(P2.z, Q2.z, B2.z, c, h1, h2); px_acc(P2.w, Q2.w, B2.w, c, h1, h2);
        px_acc(P3.x, Q3.x, B3.x, c, h1, h2); px_acc(P3.y, Q3.y, B3.y, c, h1, h2);
        px_acc(P3.z, Q3.z, B3.z, c, h1, h2); px_acc(P3.w, Q3.w, B3.w, c, h1, h2);
    }
    __syncthreads();

    // combine 32 copies for bin=tid; reads are 2-way banked (free)
    float t1 = 0.f, t2 = 0.f;
    #pragma unroll
    for (int cc = 0; cc < 32; ++cc) {
        int j = (tid + cc) & 255;
        t1 += h[0][cc][j];
        t2 += h[1][cc][j];
    }
    unsafeAtomicAdd(&S1[b * NBINS + tid], t1);
    unsafeAtomicAdd(&S2[b * NBINS + tid], t2);
}

// ---------------- finalize: per-batch closed-form sum over bins ----------------
__global__ __launch_bounds__(256) void finalize(const float* __restrict__ S1,
                                                const float* __restrict__ S2,
                                                const int* __restrict__ counts,
                                                float* __restrict__ out) {
    const int b = blockIdx.x;
    const int t = threadIdx.x;
    float contrib = 0.f;
    if (t > 3) {   // valid bins are 4..255
        float c = (float)counts[t];
        float s1 = S1[b * NBINS + t];
        float s2 = S2[b * NBINS + t];
        float mean = s1 / fmaxf(c, 1.f);
        float ssq = fmaxf(s2 - mean * s1, 0.f);          // = sum (a - mean)^2
        float var = ssq / fmaxf(c - 1.f, 1.f);
        contrib = -0.5f * s2 / var - c * logf(6.283185307179586f * var);
    }
    #pragma unroll
    for (int off = 32; off > 0; off >>= 1) contrib += __shfl_down(contrib, off, 64);
    __shared__ float w[4];
    if ((t & 63) == 0) w[t >> 6] = contrib;
    __syncthreads();
    if (t == 0) out[b] = w[0] + w[1] + w[2] + w[3];
}

extern "C" void kernel_launch(void* const* d_in, const int* in_sizes, int n_in,
                              void* d_out, int out_size, void* d_ws, size_t ws_size,
                              hipStream_t stream) {
    const float* parts = (const float*)d_in[0];
    const float* projs = (const float*)d_in[1];
    const int* bins    = (const int*)d_in[2];
    float* out = (float*)d_out;

    int*   counts = (int*)d_ws;                       // 256 ints
    float* S1 = (float*)((char*)d_ws + 1024);         // NB*NBINS floats
    float* S2 = S1 + (size_t)NB * NBINS;              // NB*NBINS floats

    size_t zero_bytes = 1024 + 2 * (size_t)NB * NBINS * sizeof(float);
    hipMemsetAsync(d_ws, 0, zero_bytes, stream);

    counts_kernel<<<256, 256, 0, stream>>>(bins, counts);
    pass1<<<dim3(P1_BLOCKS_X, NB), 256, 0, stream>>>(parts, projs, bins, S1, S2);
    finalize<<<NB, 256, 0, stream>>>(S1, S2, counts, out);
}